// Round 7
// baseline (279.393 us; speedup 1.0000x reference)
//
#include <hip/hip_runtime.h>

// loss = a*sum(pn^2) + 2*sum(z)*sum(pn) + sum(z^2)*(N - a)
//   z = (margin - p) on positives, pn = p on negatives, a = #positives.
// Streaming reduction: 256 MiB read, one scalar out.
//
// R6 post-mortem: 8-deep LDS-DMA staging (64KB/CU in flight) = same 97us as
// 4-deep VGPR loads -> NOT latency-bound anymore. Harness's own d2d restore
// runs at ~3.0 TB/s (173us fixed gap / 512MB); we're at 2.77 TB/s. In-container
// memory ceiling ~3 TB/s. R7: close the last ~10% with a barrier-free per-wave
// DMA pipeline (each wave consumes only its own LDS -> no __syncthreads in the
// stream loop; 4-slot ring, issue k+3 / s_waitcnt vmcnt(6) / consume k) so the
// DMA queue never drains. If neutral: ceiling confirmed, roofline.

constexpr float MARGIN = 1.0f;

#define BANK_STRIDE 32            // floats; 128 B = one L2 line per bank
#define BLOCK 256
#define WAVES 4                   // 256/64
#define SLOTS 4                   // ring-buffer depth (chunks)
#define CPW 16                    // chunks per wave (fast path, compile-time)
#define CHUNK 64                  // float4-groups per chunk (1 KB per array)
#define GROUPS_PER_WAVE (CPW * CHUNK)               // 1024
#define GROUPS_PER_BLOCK (WAVES * GROUPS_PER_WAVE)  // 4096

#define GLOBAL_AS __attribute__((address_space(1)))
#define LDS_AS    __attribute__((address_space(3)))

__device__ __forceinline__ float wave_reduce(float v) {
    #pragma unroll
    for (int off = 32; off > 0; off >>= 1) v += __shfl_down(v, off, 64);
    return v;
}

__global__ __launch_bounds__(BLOCK) void hinge2_reduce(
    const float* __restrict__ pred, const int* __restrict__ lab,
    float* __restrict__ ws, int nvec, int nbanks, int bank_stride)
{
    const float4* p4 = reinterpret_cast<const float4*>(pred);
    const int4*   l4 = reinterpret_cast<const int4*>(lab);

    __shared__ float4 spred[WAVES][SLOTS][CHUNK];   // 16 KB
    __shared__ int4   slab [WAVES][SLOTS][CHUNK];   // 16 KB

    float a = 0.f, sz = 0.f, sz2 = 0.f, sp = 0.f, sp2 = 0.f;

    #define ACC(px, lx) do {                         \
        float ispos = ((lx) == 1) ? 1.0f : 0.0f;     \
        float z  = ispos * (MARGIN - (px));          \
        a   += ispos;                                \
        sz  += z;                                    \
        sz2 += z * z;                                \
        float pn = ((lx) == 1) ? 0.0f : (px);        \
        sp  += pn;                                   \
        sp2 += pn * pn;                              \
    } while (0)
    #define ACC4(p, l) do {                          \
        ACC((p).x, (l).x); ACC((p).y, (l).y);        \
        ACC((p).z, (l).z); ACC((p).w, (l).w);        \
    } while (0)

    const int lane  = threadIdx.x & 63;
    const int wid   = threadIdx.x >> 6;
    const int gbase = (blockIdx.x * WAVES + wid) * GROUPS_PER_WAVE;

    // issue chunk c: two 1KB fire-and-forget DMAs (pred + lab) into slot c&3.
    // global addr is per-lane; LDS dest is wave-uniform base + lane*16 (m104).
    #define ISSUE(c) do {                                                     \
        int gg = gbase + (c) * CHUNK + lane;                                  \
        __builtin_amdgcn_global_load_lds(                                     \
            (const GLOBAL_AS void*)(p4 + gg),                                 \
            (LDS_AS void*)&spred[wid][(c) & (SLOTS - 1)][0], 16, 0, 0);       \
        __builtin_amdgcn_global_load_lds(                                     \
            (const GLOBAL_AS void*)(l4 + gg),                                 \
            (LDS_AS void*)&slab [wid][(c) & (SLOTS - 1)][0], 16, 0, 0);       \
    } while (0)

    if (gbase + GROUPS_PER_WAVE <= nvec) {
        // ---- per-wave pipelined fast path: no barriers in the stream loop ----
        ISSUE(0); ISSUE(1); ISSUE(2);           // prologue: 6 DMAs outstanding
        #pragma unroll
        for (int k = 0; k < CPW; ++k) {
            if (k + 3 < CPW) ISSUE(k + 3);      // steady state: 8 outstanding
            // wait until chunk k's 2 DMAs (the oldest) have landed in LDS
            if      (k <  CPW - 3) asm volatile("s_waitcnt vmcnt(6)" ::: "memory");
            else if (k == CPW - 3) asm volatile("s_waitcnt vmcnt(4)" ::: "memory");
            else if (k == CPW - 2) asm volatile("s_waitcnt vmcnt(2)" ::: "memory");
            else                   asm volatile("s_waitcnt vmcnt(0)" ::: "memory");
            float4 p = spred[wid][k & (SLOTS - 1)][lane];
            int4   l = slab [wid][k & (SLOTS - 1)][lane];
            ACC4(p, l);
        }
    } else {
        // edge wave: guarded plain loads (unused for N = 2^25)
        for (int c = 0; c < CPW; ++c) {
            int g = gbase + c * CHUNK + lane;
            if (g < nvec) {
                float4 p = p4[g];
                int4   l = l4[g];
                ACC4(p, l);
            }
        }
    }
    #undef ISSUE
    #undef ACC4
    #undef ACC

    a   = wave_reduce(a);
    sz  = wave_reduce(sz);
    sz2 = wave_reduce(sz2);
    sp  = wave_reduce(sp);
    sp2 = wave_reduce(sp2);

    __shared__ float sdata[WAVES][5];
    if (lane == 0) {
        sdata[wid][0] = a;
        sdata[wid][1] = sz;
        sdata[wid][2] = sz2;
        sdata[wid][3] = sp;
        sdata[wid][4] = sp2;
    }
    __syncthreads();   // only barrier in the kernel

    if (threadIdx.x == 0) {
        float t0 = 0.f, t1 = 0.f, t2 = 0.f, t3 = 0.f, t4 = 0.f;
        #pragma unroll
        for (int w = 0; w < WAVES; ++w) {
            t0 += sdata[w][0];
            t1 += sdata[w][1];
            t2 += sdata[w][2];
            t3 += sdata[w][3];
            t4 += sdata[w][4];
        }
        float* bank = ws + (blockIdx.x & (nbanks - 1)) * bank_stride;
        atomicAdd(&bank[0], t0);
        atomicAdd(&bank[1], t1);
        atomicAdd(&bank[2], t2);
        atomicAdd(&bank[3], t3);
        atomicAdd(&bank[4], t4);
    }
}

__global__ __launch_bounds__(256) void hinge2_final(
    const float* __restrict__ ws,
    const float* __restrict__ pred, const int* __restrict__ lab,
    float* __restrict__ out, int n, int tail_start,
    int nbanks, int bank_stride)
{
    int t = threadIdx.x;
    float a = 0.f, sz = 0.f, sz2 = 0.f, sp = 0.f, sp2 = 0.f;
    for (int b = t; b < nbanks; b += 256) {
        const float* bank = ws + b * bank_stride;
        a   += bank[0];
        sz  += bank[1];
        sz2 += bank[2];
        sp  += bank[3];
        sp2 += bank[4];
    }
    a   = wave_reduce(a);
    sz  = wave_reduce(sz);
    sz2 = wave_reduce(sz2);
    sp  = wave_reduce(sp);
    sp2 = wave_reduce(sp2);

    __shared__ float sdata[4][5];
    int lane = t & 63, wid = t >> 6;
    if (lane == 0) {
        sdata[wid][0] = a;  sdata[wid][1] = sz; sdata[wid][2] = sz2;
        sdata[wid][3] = sp; sdata[wid][4] = sp2;
    }
    __syncthreads();

    if (t == 0) {
        double A = 0, SZ = 0, SZ2 = 0, SP = 0, SP2 = 0;
        #pragma unroll
        for (int w = 0; w < 4; ++w) {
            A   += sdata[w][0];
            SZ  += sdata[w][1];
            SZ2 += sdata[w][2];
            SP  += sdata[w][3];
            SP2 += sdata[w][4];
        }
        for (int i = tail_start; i < n; ++i) {
            float p = pred[i];
            if (lab[i] == 1) {
                double z = (double)MARGIN - (double)p;
                A += 1.0; SZ += z; SZ2 += z * z;
            } else {
                SP += (double)p; SP2 += (double)p * (double)p;
            }
        }
        double loss = A * SP2 + 2.0 * SZ * SP + SZ2 * ((double)n - A);
        out[0] = (float)loss;
    }
}

extern "C" void kernel_launch(void* const* d_in, const int* in_sizes, int n_in,
                              void* d_out, int out_size, void* d_ws, size_t ws_size,
                              hipStream_t stream)
{
    const float* pred = (const float*)d_in[0];
    const int*   lab  = (const int*)d_in[1];
    float*       out  = (float*)d_out;
    float*       ws   = (float*)d_ws;

    int n    = in_sizes[0];
    int nvec = n >> 2;          // float4 / int4 groups
    int tail = nvec << 2;

    int bank_stride = BANK_STRIDE;
    size_t max_banks = ws_size / (bank_stride * sizeof(float));
    int nbanks = 1;
    if (max_banks == 0) { bank_stride = 5; nbanks = 1; }
    else { while (nbanks * 2 <= (int)max_banks && nbanks < 256) nbanks <<= 1; }

    // ws is re-poisoned to 0xAA before every timed launch — zero the banks
    hipMemsetAsync(ws, 0, (size_t)nbanks * bank_stride * sizeof(float), stream);

    int blocks = (nvec + GROUPS_PER_BLOCK - 1) / GROUPS_PER_BLOCK;  // 2048
    if (blocks < 1) blocks = 1;
    hinge2_reduce<<<blocks, BLOCK, 0, stream>>>(pred, lab, ws, nvec, nbanks, bank_stride);
    hinge2_final<<<1, BLOCK, 0, stream>>>(ws, pred, lab, out, n, tail, nbanks, bank_stride);
}